// Round 9
// baseline (124.579 us; speedup 1.0000x reference)
//
#include <hip/hip_runtime.h>
#include <climits>

#define HW 262144          // 512*512
#define IW 512
#define RN 725             // virtual rotated canvas side
#define NSEG 256
#define CH_OFF 1536
#define TH_OFF 116736
#define XY_OFF 485376
#define NBLK 256           // grad tiles per plane; minmax partial count
#define THP 16             // pixel splits in thist (r23: 24->16, K2 single residency round)
#define CHP 32             // pixel splits in regchist role

// grad tile geometry (r16): output tile 64x16; rotated source box 24x72 at (-156,-156).
#define ASTR 67
#define RSTR 73
#define ROFF 156

static __device__ __forceinline__ float rtap_l(const float* __restrict__ Rt,
                                               int rx0, int ry0, int cx, int cy) {
    if (cx < 0 || cx >= RN || cy < 0 || cy >= RN) return 0.f;
    const float cs = 0.7071067811865476f;
    float xg = (float)cx - 362.0f;
    float yg = (float)cy - 362.0f;
    float xi = cs * xg - cs * yg + 255.5f;
    float yi = cs * xg + cs * yg + 255.5f;
    int xs = (int)rintf(xi);
    int ys = (int)rintf(yi);
    if (xs < 0 || xs >= IW || ys < 0 || ys >= IW) return 0.f;
    return Rt[(ys - ry0) * RSTR + (xs - rx0)];
}

// block-level min/max of map m's NBLK partials; all threads get (mn,mx)
static __device__ __forceinline__ void mm_of_map(const float* __restrict__ pmin,
                                                 const float* __restrict__ pmax,
                                                 int m, float* slo, float* shi,
                                                 float& mn, float& mx) {
    int tid = threadIdx.x;
    float lo = 3.4e38f, hi = -3.4e38f;
    for (int i = tid; i < NBLK; i += 256) {
        lo = fminf(lo, pmin[m * NBLK + i]);
        hi = fmaxf(hi, pmax[m * NBLK + i]);
    }
    slo[tid] = lo; shi[tid] = hi;
    __syncthreads();
    for (int off = 128; off > 0; off >>= 1) {
        if (tid < off) {
            slo[tid] = fminf(slo[tid], slo[tid + off]);
            shi[tid] = fmaxf(shi[tid], shi[tid + off]);
        }
        __syncthreads();
    }
    mn = slo[0]; mx = shi[0];
    __syncthreads();
}

// ==== K1 (r23): grad (1536) || packed-regchist (576), 8:3 mod-11 ====
// r23: region/bbox duty spread over ALL rows: block (gy,sp) does region
// updates only on grid-stride iterations with itc%3==c (each (sp,itc) cell
// covered by exactly one c -> disjoint, exact, zero extra loads). Kills the
// 6x per-block skew of the old c==0-only scheme. Partials: [bg][sp][c]=96 slots.
__global__ __launch_bounds__(256) void k_front(
    const float* __restrict__ img, const int* __restrict__ lab,
    float* __restrict__ gmaps, float* __restrict__ pmin, float* __restrict__ pmax,
    unsigned char* __restrict__ lab8, unsigned* __restrict__ chp_w,
    unsigned* __restrict__ rsp, int* __restrict__ bxmin, int* __restrict__ bxmax,
    int* __restrict__ bymin, int* __restrict__ bymax)
{
    __shared__ __align__(16) unsigned char smem[20480];
    int bxid = blockIdx.x;
    int tid = threadIdx.x;
    int grp = bxid / 11, rem = bxid % 11;   // 2112 = 192*11
    if (rem < 8) {
        // ---- grad role: u in [0,1536): tile (u&255), plane bc=(u>>8) ----
        int u = grp * 8 + rem;
        int tile = u & 255;
        int bc = u >> 8;
        float* At = (float*)smem;                               // 1206 f
        float* Rt = At + 18 * ASTR;                             // 1752 f
        float (*slo)[256] = (float (*)[256])(Rt + 24 * RSTR);   // 4*256 f
        float (*shi)[256] = slo + 4;                            // 4*256 f (20024 B)
        // u8 label pack for k_thist: 256 blocks/plane * 256 thr * 4 == HW
        {
            int i = tile * 256 + tid;
            int4 l = ((const int4*)(lab + (size_t)bc * HW))[i];
            unsigned v = (unsigned)(l.x & 255) | ((unsigned)(l.y & 255) << 8) |
                         ((unsigned)(l.z & 255) << 16) | ((unsigned)(l.w & 255) << 24);
            ((unsigned*)(lab8 + (size_t)bc * HW))[i] = v;
        }
        int tx0 = (tile & 7) << 6;
        int ty0 = (tile >> 3) << 4;
        const float* im = img + (size_t)bc * HW;
        int lane = tid & 63, wr = tid >> 6;
        for (int r = wr; r < 18; r += 4) {
            int gy = ty0 - 1 + r;
            bool yok = (gy >= 0 && gy < IW);
            int gx = tx0 - 1 + lane;
            At[r * ASTR + lane] = (yok && gx >= 0 && gx < IW) ? im[gy * IW + gx] : 0.f;
            if (lane < 2) {
                int gx2 = gx + 64;
                At[r * ASTR + lane + 64] = (yok && gx2 >= 0 && gx2 < IW) ? im[gy * IW + gx2] : 0.f;
            }
        }
        for (int r = wr; r < 24; r += 4) {
            int gy = ty0 - ROFF + r;
            bool yok = (gy >= 0 && gy < IW);
            int gx = tx0 - ROFF + lane;
            Rt[r * RSTR + lane] = (yok && gx >= 0 && gx < IW) ? im[gy * IW + gx] : 0.f;
            if (lane < 8) {
                int gx2 = gx + 64;
                Rt[r * RSTR + lane + 64] = (yok && gx2 >= 0 && gx2 < IW) ? im[gy * IW + gx2] : 0.f;
            }
        }
        __syncthreads();
        const float cs = 0.7071067811865476f;
        int rx0 = tx0 - ROFF, ry0 = ty0 - ROFF;
        float mn0 = 3.4e38f, mx0 = -3.4e38f, mn1 = 3.4e38f, mx1 = -3.4e38f;
        float mn2 = 3.4e38f, mx2 = -3.4e38f, mn3 = 3.4e38f, mx3 = -3.4e38f;
        #pragma unroll
        for (int it = 0; it < 4; ++it) {
            int ly = wr * 4 + it;
            int x = tx0 + lane, y = ty0 + ly;
            int p = y * IW + x;
            const float* Ar = At + ly * ASTR + lane;
            float a  = Ar[0],            b2 = Ar[1],            c2 = Ar[2];
            float d2 = Ar[ASTR],                                 e2 = Ar[ASTR + 2];
            float f2 = Ar[2 * ASTR],     h2 = Ar[2 * ASTR + 1], i9 = Ar[2 * ASTR + 2];
            float g0 = -3.f*a + 3.f*c2 + 10.f*d2 + 10.f*e2 - 3.f*f2 + 3.f*i9;
            float g1 = -3.f*a + 10.f*b2 - 3.f*c2 + 3.f*f2 + 10.f*h2 + 3.f*i9;
            gmaps[((size_t)(bc*2+0))*HW + p] = g0;
            gmaps[((size_t)(bc*2+1))*HW + p] = g1;
            float xgc = (float)(x + 105) - 512.5f;
            float ygc = (float)(y + 105) - 512.5f;
            float t1 = cs * xgc, t2 = cs * ygc;
            float xi = (t1 + t2) + 362.0f;
            float yi = (-t1 + t2) + 362.0f;
            int xn = (int)rintf(xi);
            int yn = (int)rintf(yi);
            float r0 = 0.f, r1 = 0.f;
            if (xn >= 0 && xn < RN && yn >= 0 && yn < RN) {
                float ra = rtap_l(Rt, rx0, ry0, xn-1, yn-1);
                float rb = rtap_l(Rt, rx0, ry0, xn,   yn-1);
                float rc = rtap_l(Rt, rx0, ry0, xn+1, yn-1);
                float rd = rtap_l(Rt, rx0, ry0, xn-1, yn);
                float re = rtap_l(Rt, rx0, ry0, xn+1, yn);
                float rf = rtap_l(Rt, rx0, ry0, xn-1, yn+1);
                float rh = rtap_l(Rt, rx0, ry0, xn,   yn+1);
                float ri = rtap_l(Rt, rx0, ry0, xn+1, yn+1);
                r0 = -3.f*ra + 3.f*rc + 10.f*rd + 10.f*re - 3.f*rf + 3.f*ri;
                r1 = -3.f*ra + 10.f*rb - 3.f*rc + 3.f*rf + 10.f*rh + 3.f*ri;
            }
            gmaps[((size_t)(12 + bc*2+0))*HW + p] = r0;
            gmaps[((size_t)(12 + bc*2+1))*HW + p] = r1;
            mn0 = fminf(mn0, g0); mx0 = fmaxf(mx0, g0);
            mn1 = fminf(mn1, g1); mx1 = fmaxf(mx1, g1);
            mn2 = fminf(mn2, r0); mx2 = fmaxf(mx2, r0);
            mn3 = fminf(mn3, r1); mx3 = fmaxf(mx3, r1);
        }
        slo[0][tid] = mn0; shi[0][tid] = mx0;
        slo[1][tid] = mn1; shi[1][tid] = mx1;
        slo[2][tid] = mn2; shi[2][tid] = mx2;
        slo[3][tid] = mn3; shi[3][tid] = mx3;
        __syncthreads();
        for (int off = 128; off > 0; off >>= 1) {
            if (tid < off) {
                #pragma unroll
                for (int k = 0; k < 4; ++k) {
                    slo[k][tid] = fminf(slo[k][tid], slo[k][tid + off]);
                    shi[k][tid] = fmaxf(shi[k][tid], shi[k][tid + off]);
                }
            }
            __syncthreads();
        }
        if (tid < 4) {
            int m = (tid < 2) ? (bc*2 + tid) : (12 + bc*2 + (tid - 2));
            pmin[m * NBLK + tile] = slo[tid][0];
            pmax[m * NBLK + tile] = shi[tid][0];
        }
    } else {
        // ---- packed regchist role: w in [0,576): row gy=w>>5, split sp=w&31 ----
        int w = grp * 3 + (rem - 8);
        int gy = w >> 5;           // (b*3+g)*3 + c
        int sp = w & 31;
        int c = gy % 3;
        int bg = gy / 3;
        int b = bg / 3;
        unsigned* pk = (unsigned*)smem;             // 3200 words (6400 u16 bins)
        unsigned* prc = pk + 3200;                  // 128 words (256 u16 rcnt)
        int* sxmin = (int*)(prc + 128);             // 4x256 int (17408 B total)
        int* sxmax = sxmin + NSEG;
        int* symin = sxmax + NSEG;
        int* symax = symin + NSEG;
        for (int i = tid; i < 3200; i += 256) pk[i] = 0;
        if (tid < 128) prc[tid] = 0;
        sxmin[tid] = INT_MAX; sxmax[tid] = INT_MIN;
        symin[tid] = INT_MAX; symax[tid] = INT_MIN;
        __syncthreads();
        const float4* ip = (const float4*)(img + ((size_t)b * 3 + c) * HW);
        const int4* lp = (const int4*)(lab + (size_t)bg * HW);
        int itc = 0;
        for (int i = sp * 256 + tid; i < HW / 4; i += 256 * CHP, ++itc) {
            float4 v4 = ip[i];
            int4 l4 = lp[i];
            int l0 = l4.x & 255, l1 = l4.y & 255, l2 = l4.z & 255, l3 = l4.w & 255;
            int b0 = (int)((float)l0 * 25.0f + v4.x * 24.0f);
            int b1 = (int)((float)l1 * 25.0f + v4.y * 24.0f);
            int b2 = (int)((float)l2 * 25.0f + v4.z * 24.0f);
            int b3 = (int)((float)l3 * 25.0f + v4.w * 24.0f);
            b0 = min(max(b0, 0), 6399); b1 = min(max(b1, 0), 6399);
            b2 = min(max(b2, 0), 6399); b3 = min(max(b3, 0), 6399);
            atomicAdd(&pk[b0 >> 1], 1u << ((b0 & 1) << 4));
            atomicAdd(&pk[b1 >> 1], 1u << ((b1 & 1) << 4));
            atomicAdd(&pk[b2 >> 1], 1u << ((b2 & 1) << 4));
            atomicAdd(&pk[b3 >> 1], 1u << ((b3 & 1) << 4));
            if (itc % 3 == c) {
                int p = i << 2;
                int y = p >> 9, x = p & 511;
                atomicAdd(&prc[l0 >> 1], 1u << ((l0 & 1) << 4));
                atomicAdd(&prc[l1 >> 1], 1u << ((l1 & 1) << 4));
                atomicAdd(&prc[l2 >> 1], 1u << ((l2 & 1) << 4));
                atomicAdd(&prc[l3 >> 1], 1u << ((l3 & 1) << 4));
                atomicMin(&sxmin[l0], x);     atomicMax(&sxmax[l0], x);
                atomicMin(&sxmin[l1], x + 1); atomicMax(&sxmax[l1], x + 1);
                atomicMin(&sxmin[l2], x + 2); atomicMax(&sxmax[l2], x + 2);
                atomicMin(&sxmin[l3], x + 3); atomicMax(&sxmax[l3], x + 3);
                atomicMin(&symin[l0], y); atomicMax(&symax[l0], y);
                atomicMin(&symin[l1], y); atomicMax(&symax[l1], y);
                atomicMin(&symin[l2], y); atomicMax(&symax[l2], y);
                atomicMin(&symin[l3], y); atomicMax(&symax[l3], y);
            }
        }
        __syncthreads();
        unsigned* dst = chp_w + ((size_t)gy * CHP + sp) * 3200;
        for (int i = tid; i < 3200; i += 256) dst[i] = pk[i];
        size_t pi = (size_t)((bg * 32 + sp) * 3 + c) * NSEG + tid;   // 96 slots per bg
        rsp[pi] = (prc[tid >> 1] >> ((tid & 1) << 4)) & 0xFFFFu;
        bxmin[pi] = sxmin[tid]; bxmax[pi] = sxmax[tid];
        bymin[pi] = symin[tid]; bymax[pi] = symax[tid];
    }
}

// ==== K2 (r23): thist (1152, THP=16) || ch-final riders (384 x 4 segs) ====
// 1536 blocks <= 1792 residency slots (7/CU @ 22.5KB) -> SINGLE scheduling
// round (r22 ran 2496 blocks = two rounds, second at ~40% occupancy).
__global__ __launch_bounds__(256) void k_hist(
    const float* __restrict__ maps, const unsigned char* __restrict__ lab8,
    const float* __restrict__ pmin, const float* __restrict__ pmax,
    unsigned* __restrict__ thp_w, const unsigned* __restrict__ chp_w,
    const unsigned* __restrict__ rsp,
    const int* __restrict__ bxmin, const int* __restrict__ bxmax,
    const int* __restrict__ bymin, const int* __restrict__ bymax,
    float* __restrict__ out)
{
    __shared__ __align__(16) unsigned char smem[22528];
    int bx = blockIdx.x;
    int tid = threadIdx.x;
    if (bx < 1152) {
        // ---- thist role ----
        unsigned* cnt = (unsigned*)smem;            // 5120 u32
        float* slo = (float*)(smem + 20480);
        float* shi = slo + 256;
        int gy = bx >> 4;
        int split = bx & 15;
        int gi = gy % 3;
        int r = gy / 3;
        int base = r & 1;
        int bd = r >> 1;
        int d = bd & 1;
        int bc = bd >> 1;
        int b = bc / 3;
        int m = base * 12 + bc * 2 + d;
        float mn, mx;
        mm_of_map(pmin, pmax, m, slo, shi, mn, mx);
        for (int i = tid; i < 5120; i += 256) cnt[i] = 0;
        __syncthreads();
        float hminp = fmaxf(mn, 0.f), denp = fmaxf(mx, 0.f) - hminp;
        float hminn = fminf(mn, 0.f), denn = fminf(mx, 0.f) - hminn;
        const float4* src = (const float4*)(maps + (size_t)m * HW);
        const unsigned* lp = (const unsigned*)(lab8 + (size_t)(b * 3 + gi) * HW);
        for (int i = split * 256 + tid; i < HW / 4; i += 256 * THP) {
            float4 v4 = src[i];
            unsigned l4 = lp[i];
#define TH1(V, SH)                                                     \
            {                                                          \
                float v = (V);                                         \
                bool ge = (v >= 0.f);                                  \
                float hm = ge ? hminp : hminn;                         \
                float dn = ge ? denp : denn;                           \
                float t9 = ((v - hm) / dn) * 9.0f;                     \
                int bi = (int)((float)((l4 >> SH) & 255u) * 10.0f + t9); \
                bi = min(max(bi, 0), 2559);                            \
                atomicAdd(&cnt[(ge ? 0 : 2560) + bi], 1u);             \
            }
            TH1(v4.x, 0) TH1(v4.y, 8) TH1(v4.z, 16) TH1(v4.w, 24)
#undef TH1
        }
        __syncthreads();
        unsigned* dst = thp_w + ((size_t)(gy * THP + split)) * 2560;
        for (int i = tid; i < 2560; i += 256)
            dst[i] = cnt[2 * i] | (cnt[2 * i + 1] << 16);
    } else {
        // ---- ch-final rider: 4 segs/block, 2 passes of 2 segs; LDS staging ----
        unsigned* crs2 = (unsigned*)smem;            // [2][96]
        int* xm = (int*)(crs2 + 192);                // [2][96] each
        int* xM = xm + 192;
        int* ym = xM + 192;
        int* yM = ym + 192;                          // total 960 words (3840 B)
        int j = bx - 1152;                 // [0,384)
        int seg0 = j * 4;
        int bg = seg0 >> 8;                // 256%4==0 -> all 4 segs same bg
        for (int ps = 0; ps < 2; ++ps) {
            int sb = (seg0 & 255) + ps * 2;          // first of this pass's 2 segs
            for (int k = tid; k < 960; k += 256) {
                int a = k / 192;
                int rk = k - a * 192;
                int h = rk / 96, p = rk - h * 96;
                size_t idx = ((size_t)(bg * 96 + p)) * NSEG + (sb + h);
                int o = h * 96 + p;
                if (a == 0)      crs2[o] = rsp[idx];
                else if (a == 1) xm[o] = bxmin[idx];
                else if (a == 2) xM[o] = bxmax[idx];
                else if (a == 3) ym[o] = bymin[idx];
                else             yM[o] = bymax[idx];
            }
            __syncthreads();
            int half = tid >> 7, t2 = tid & 127;
            int s = sb + half;
            int seg = bg * 256 + s;
            if (t2 < 75) {
                unsigned rs = 0;
                for (int p = 0; p < 96; ++p) rs += crs2[half * 96 + p];
                float rsf = (float)rs;
                int cc = t2 / 25, cb = t2 - cc * 25;
                int bin = s * 25 + cb;
                unsigned sum = 0;
                #pragma unroll 4
                for (int p = 0; p < CHP; ++p) {
                    unsigned v = chp_w[((size_t)((bg * 3 + cc) * CHP + p)) * 3200 + (bin >> 1)];
                    sum += (v >> ((bin & 1) << 4)) & 0xFFFFu;
                }
                out[CH_OFF + (size_t)seg * 75 + t2] = (float)sum / (3.0f * rsf);
            } else if (t2 == 75) {
                unsigned rs = 0;
                for (int p = 0; p < 96; ++p) rs += crs2[half * 96 + p];
                float rsf = (float)rs;
                out[seg] = rsf;
                int xmn = INT_MAX, xmx = INT_MIN, ymn = INT_MAX, ymx = INT_MIN;
                for (int p = 0; p < 96; ++p) {
                    xmn = min(xmn, xm[half * 96 + p]); xmx = max(xmx, xM[half * 96 + p]);
                    ymn = min(ymn, ym[half * 96 + p]); ymx = max(ymx, yM[half * 96 + p]);
                }
                if (!(rsf > 0.f)) { xmn = IW; ymn = IW; xmx = 0; ymx = 0; }
                float* xy = out + XY_OFF + (size_t)seg * 4;
                xy[0] = (float)xmn; xy[1] = (float)ymn;
                xy[2] = (float)(xmx - xmn); xy[3] = (float)(ymx - ymn);
            }
            __syncthreads();
        }
    }
}

// ==== K3 (r23): pure th-reduce, 576 blocks (32-label chunks); srs reduced
//      thread-parallel via 32x8 two-level LDS sum (r5 serial-walk fix) ====
__global__ __launch_bounds__(256) void k_final(
    const unsigned* __restrict__ thp_w, const unsigned* __restrict__ rsp,
    const float* __restrict__ pmin, const float* __restrict__ pmax,
    float* __restrict__ out)
{
    __shared__ unsigned hist[640];     // [0,320) pos bins, [320,640) neg, 32 labels
    __shared__ unsigned srsp[256];     // [32 labels][8 groups of 12 partials]
    __shared__ unsigned srs[32];
    __shared__ float slo[256], shi[256];
    int tid = threadIdx.x;
    int bx = blockIdx.x;
    int gy = bx >> 3;
    int ck = bx & 7;
    int l0 = ck << 5;                  // first label of chunk
    int gi = gy % 3; int r = gy / 3; int base = r & 1;
    int bd = r >> 1; int d = bd & 1; int bc = bd >> 1;
    int b = bc / 3, c = bc - b * 3;
    int m = base * 12 + bc * 2 + d;
    int bg = b * 3 + gi;
    float mn, mx;
    mm_of_map(pmin, pmax, m, slo, shi, mn, mx);
    // reduce packed partials: 160 words/side for this chunk
    for (int w = tid; w < 320; w += 256) {
        int gw = (w < 160) ? (l0 * 5 + w) : (1280 + l0 * 5 + (w - 160));
        unsigned s0 = 0, s1 = 0;
        #pragma unroll 4
        for (int p = 0; p < THP; ++p) {
            unsigned v = thp_w[((size_t)(gy * THP + p)) * 2560 + gw];
            s0 += v & 0xFFFFu; s1 += v >> 16;
        }
        int bi = (w < 160) ? (2 * w) : (320 + 2 * (w - 160));
        hist[bi] = s0; hist[bi + 1] = s1;
    }
    {
        int l = tid >> 3, g = tid & 7;     // 32 labels x 8 groups
        unsigned s = 0;
        for (int p = g * 12; p < g * 12 + 12; ++p)
            s += rsp[((size_t)(bg * 96 + p)) * NSEG + l0 + l];
        srsp[tid] = s;
    }
    __syncthreads();
    if (tid < 32) {
        unsigned s = 0;
        #pragma unroll
        for (int g = 0; g < 8; ++g) s += srsp[tid * 8 + g];
        srs[tid] = s;
        int l = l0 + tid;   // this chunk's labels: sign-completion
        unsigned nge = 0;
        for (int tb = 0; tb < 10; ++tb) nge += hist[tid * 10 + tb];  // v>=0 count
        unsigned rsu = s;
        unsigned nlt = (rsu >= nge) ? (rsu - nge) : 0u;              // v<0 count
        float hminp = fmaxf(mn, 0.f), denp = fmaxf(mx, 0.f) - hminp;
        float hminn = fminf(mn, 0.f), denn = fminf(mx, 0.f) - hminn;
        float la = (float)l;
        float tp0 = ((0.0f - hminp) / denp) * 9.0f;  // pos bin of clipped (v<0)
        float tn0 = ((0.0f - hminn) / denn) * 9.0f;  // neg bin of clipped (v>=0)
        int g0off = l0 * 10;
        int bp = (int)(la * 10.0f + tp0); bp = min(max(bp, 0), 2559);
        int bn = (int)(la * 10.0f + tn0); bn = min(max(bn, 0), 2559);
        if (nlt && bp >= g0off && bp < g0off + 320) atomicAdd(&hist[bp - g0off], nlt);
        if (nge && bn >= g0off && bn < g0off + 320) atomicAdd(&hist[320 + bn - g0off], nge);
    }
    __syncthreads();
    for (int i = tid; i < 640; i += 256) {
        int pos = (i < 320);
        int rr = pos ? i : i - 320;
        int lseg = rr / 10, tb = rr % 10;
        int seg = l0 + lseg;
        int tt = base * 4 + (pos ? 0 : 2) + d;
        float rsf = (float)srs[lseg];
        out[TH_OFF + ((size_t)(bg * NSEG + seg) * 3 + c) * 80 + tt * 10 + tb] =
            (float)hist[i] / (24.0f * rsf);
    }
}

extern "C" void kernel_launch(void* const* d_in, const int* in_sizes, int n_in,
                              void* d_out, int out_size, void* d_ws, size_t ws_size,
                              hipStream_t stream) {
    const float* img = (const float*)d_in[0];
    const int* lab = (const int*)d_in[1];
    float* out = (float*)d_out;

    float* gmaps = (float*)d_ws;                        // 24 maps * 262144 f32 (25.2 MB)
    float* pmin = gmaps + (size_t)24 * HW;              // 24*NBLK
    float* pmax = pmin + 24 * NBLK;
    unsigned* thp_w = (unsigned*)(pmax + 24 * NBLK);    // 72*THP*2560 u32 (~11.8 MB, u16-packed)
    unsigned* chp_w = thp_w + (size_t)72 * THP * 2560;  // 18*CHP*3200 u32 (~7.4 MB, u16-packed)
    unsigned char* lab8 = (unsigned char*)(chp_w + (size_t)18 * CHP * 3200);  // 6*HW u8
    unsigned* rsp = (unsigned*)(lab8 + (size_t)6 * HW); // 6*96*256 u32
    int* bxmin = (int*)(rsp + 6 * 96 * NSEG);
    int* bxmax = bxmin + 6 * 96 * NSEG;
    int* bymin = bxmax + 6 * 96 * NSEG;
    int* bymax = bymin + 6 * 96 * NSEG;

    hipLaunchKernelGGL(k_front, dim3(2112), dim3(256), 0, stream,
                       img, lab, gmaps, pmin, pmax, lab8, chp_w, rsp, bxmin, bxmax, bymin, bymax);
    hipLaunchKernelGGL(k_hist, dim3(1152 + 384), dim3(256), 0, stream,
                       gmaps, lab8, pmin, pmax, thp_w, chp_w, rsp, bxmin, bxmax, bymin, bymax, out);
    hipLaunchKernelGGL(k_final, dim3(576), dim3(256), 0, stream,
                       thp_w, rsp, pmin, pmax, out);
}

// Round 10
// 115.917 us; speedup vs baseline: 1.0747x; 1.0747x over previous
//
#include <hip/hip_runtime.h>
#include <climits>

#define HW 262144          // 512*512
#define IW 512
#define RN 725             // virtual rotated canvas side
#define NSEG 256
#define CH_OFF 1536
#define TH_OFF 116736
#define XY_OFF 485376
#define NBLK 256           // grad tiles per plane; minmax partial count
#define THP 24             // pixel splits in thist
#define CHP 32             // pixel splits in regchist role

// grad tile geometry (r16): output tile 64x16; rotated source box 24x72 at (-156,-156).
#define ASTR 67
#define RSTR 73
#define ROFF 156

static __device__ __forceinline__ float rtap_l(const float* __restrict__ Rt,
                                               int rx0, int ry0, int cx, int cy) {
    if (cx < 0 || cx >= RN || cy < 0 || cy >= RN) return 0.f;
    const float cs = 0.7071067811865476f;
    float xg = (float)cx - 362.0f;
    float yg = (float)cy - 362.0f;
    float xi = cs * xg - cs * yg + 255.5f;
    float yi = cs * xg + cs * yg + 255.5f;
    int xs = (int)rintf(xi);
    int ys = (int)rintf(yi);
    if (xs < 0 || xs >= IW || ys < 0 || ys >= IW) return 0.f;
    return Rt[(ys - ry0) * RSTR + (xs - rx0)];
}

// block-level min/max of map m's NBLK partials; all threads get (mn,mx)
static __device__ __forceinline__ void mm_of_map(const float* __restrict__ pmin,
                                                 const float* __restrict__ pmax,
                                                 int m, float* slo, float* shi,
                                                 float& mn, float& mx) {
    int tid = threadIdx.x;
    float lo = 3.4e38f, hi = -3.4e38f;
    for (int i = tid; i < NBLK; i += 256) {
        lo = fminf(lo, pmin[m * NBLK + i]);
        hi = fmaxf(hi, pmax[m * NBLK + i]);
    }
    slo[tid] = lo; shi[tid] = hi;
    __syncthreads();
    for (int off = 128; off > 0; off >>= 1) {
        if (tid < off) {
            slo[tid] = fminf(slo[tid], slo[tid + off]);
            shi[tid] = fmaxf(shi[tid], shi[tid + off]);
        }
        __syncthreads();
    }
    mn = slo[0]; mx = shi[0];
    __syncthreads();
}

// ==== K1 (r21, unchanged): grad (1536) || packed-regchist (576), 8:3 mod-11 ====
__global__ __launch_bounds__(256) void k_front(
    const float* __restrict__ img, const int* __restrict__ lab,
    float* __restrict__ gmaps, float* __restrict__ pmin, float* __restrict__ pmax,
    unsigned char* __restrict__ lab8, unsigned* __restrict__ chp_w,
    unsigned* __restrict__ rsp, int* __restrict__ bxmin, int* __restrict__ bxmax,
    int* __restrict__ bymin, int* __restrict__ bymax)
{
    __shared__ __align__(16) unsigned char smem[20480];
    int bxid = blockIdx.x;
    int tid = threadIdx.x;
    int grp = bxid / 11, rem = bxid % 11;   // 2112 = 192*11
    if (rem < 8) {
        // ---- grad role: u in [0,1536): tile (u&255), plane bc=(u>>8) ----
        int u = grp * 8 + rem;
        int tile = u & 255;
        int bc = u >> 8;
        float* At = (float*)smem;                               // 1206 f
        float* Rt = At + 18 * ASTR;                             // 1752 f
        float (*slo)[256] = (float (*)[256])(Rt + 24 * RSTR);   // 4*256 f
        float (*shi)[256] = slo + 4;                            // 4*256 f (20024 B)
        // u8 label pack for k_thist: 256 blocks/plane * 256 thr * 4 == HW
        {
            int i = tile * 256 + tid;
            int4 l = ((const int4*)(lab + (size_t)bc * HW))[i];
            unsigned v = (unsigned)(l.x & 255) | ((unsigned)(l.y & 255) << 8) |
                         ((unsigned)(l.z & 255) << 16) | ((unsigned)(l.w & 255) << 24);
            ((unsigned*)(lab8 + (size_t)bc * HW))[i] = v;
        }
        int tx0 = (tile & 7) << 6;
        int ty0 = (tile >> 3) << 4;
        const float* im = img + (size_t)bc * HW;
        int lane = tid & 63, wr = tid >> 6;
        for (int r = wr; r < 18; r += 4) {
            int gy = ty0 - 1 + r;
            bool yok = (gy >= 0 && gy < IW);
            int gx = tx0 - 1 + lane;
            At[r * ASTR + lane] = (yok && gx >= 0 && gx < IW) ? im[gy * IW + gx] : 0.f;
            if (lane < 2) {
                int gx2 = gx + 64;
                At[r * ASTR + lane + 64] = (yok && gx2 >= 0 && gx2 < IW) ? im[gy * IW + gx2] : 0.f;
            }
        }
        for (int r = wr; r < 24; r += 4) {
            int gy = ty0 - ROFF + r;
            bool yok = (gy >= 0 && gy < IW);
            int gx = tx0 - ROFF + lane;
            Rt[r * RSTR + lane] = (yok && gx >= 0 && gx < IW) ? im[gy * IW + gx] : 0.f;
            if (lane < 8) {
                int gx2 = gx + 64;
                Rt[r * RSTR + lane + 64] = (yok && gx2 >= 0 && gx2 < IW) ? im[gy * IW + gx2] : 0.f;
            }
        }
        __syncthreads();
        const float cs = 0.7071067811865476f;
        int rx0 = tx0 - ROFF, ry0 = ty0 - ROFF;
        float mn0 = 3.4e38f, mx0 = -3.4e38f, mn1 = 3.4e38f, mx1 = -3.4e38f;
        float mn2 = 3.4e38f, mx2 = -3.4e38f, mn3 = 3.4e38f, mx3 = -3.4e38f;
        #pragma unroll
        for (int it = 0; it < 4; ++it) {
            int ly = wr * 4 + it;
            int x = tx0 + lane, y = ty0 + ly;
            int p = y * IW + x;
            const float* Ar = At + ly * ASTR + lane;
            float a  = Ar[0],            b2 = Ar[1],            c2 = Ar[2];
            float d2 = Ar[ASTR],                                 e2 = Ar[ASTR + 2];
            float f2 = Ar[2 * ASTR],     h2 = Ar[2 * ASTR + 1], i9 = Ar[2 * ASTR + 2];
            float g0 = -3.f*a + 3.f*c2 + 10.f*d2 + 10.f*e2 - 3.f*f2 + 3.f*i9;
            float g1 = -3.f*a + 10.f*b2 - 3.f*c2 + 3.f*f2 + 10.f*h2 + 3.f*i9;
            gmaps[((size_t)(bc*2+0))*HW + p] = g0;
            gmaps[((size_t)(bc*2+1))*HW + p] = g1;
            float xgc = (float)(x + 105) - 512.5f;
            float ygc = (float)(y + 105) - 512.5f;
            float t1 = cs * xgc, t2 = cs * ygc;
            float xi = (t1 + t2) + 362.0f;
            float yi = (-t1 + t2) + 362.0f;
            int xn = (int)rintf(xi);
            int yn = (int)rintf(yi);
            float r0 = 0.f, r1 = 0.f;
            if (xn >= 0 && xn < RN && yn >= 0 && yn < RN) {
                float ra = rtap_l(Rt, rx0, ry0, xn-1, yn-1);
                float rb = rtap_l(Rt, rx0, ry0, xn,   yn-1);
                float rc = rtap_l(Rt, rx0, ry0, xn+1, yn-1);
                float rd = rtap_l(Rt, rx0, ry0, xn-1, yn);
                float re = rtap_l(Rt, rx0, ry0, xn+1, yn);
                float rf = rtap_l(Rt, rx0, ry0, xn-1, yn+1);
                float rh = rtap_l(Rt, rx0, ry0, xn,   yn+1);
                float ri = rtap_l(Rt, rx0, ry0, xn+1, yn+1);
                r0 = -3.f*ra + 3.f*rc + 10.f*rd + 10.f*re - 3.f*rf + 3.f*ri;
                r1 = -3.f*ra + 10.f*rb - 3.f*rc + 3.f*rf + 10.f*rh + 3.f*ri;
            }
            gmaps[((size_t)(12 + bc*2+0))*HW + p] = r0;
            gmaps[((size_t)(12 + bc*2+1))*HW + p] = r1;
            mn0 = fminf(mn0, g0); mx0 = fmaxf(mx0, g0);
            mn1 = fminf(mn1, g1); mx1 = fmaxf(mx1, g1);
            mn2 = fminf(mn2, r0); mx2 = fmaxf(mx2, r0);
            mn3 = fminf(mn3, r1); mx3 = fmaxf(mx3, r1);
        }
        slo[0][tid] = mn0; shi[0][tid] = mx0;
        slo[1][tid] = mn1; shi[1][tid] = mx1;
        slo[2][tid] = mn2; shi[2][tid] = mx2;
        slo[3][tid] = mn3; shi[3][tid] = mx3;
        __syncthreads();
        for (int off = 128; off > 0; off >>= 1) {
            if (tid < off) {
                #pragma unroll
                for (int k = 0; k < 4; ++k) {
                    slo[k][tid] = fminf(slo[k][tid], slo[k][tid + off]);
                    shi[k][tid] = fmaxf(shi[k][tid], shi[k][tid + off]);
                }
            }
            __syncthreads();
        }
        if (tid < 4) {
            int m = (tid < 2) ? (bc*2 + tid) : (12 + bc*2 + (tid - 2));
            pmin[m * NBLK + tile] = slo[tid][0];
            pmax[m * NBLK + tile] = shi[tid][0];
        }
    } else {
        // ---- packed regchist role: w in [0,576): row gy=w>>5, split sp=w&31 ----
        int w = grp * 3 + (rem - 8);
        int gy = w >> 5;           // (b*3+g)*3 + c
        int sp = w & 31;
        int c = gy % 3;
        int bg = gy / 3;
        int b = bg / 3;
        unsigned* pk = (unsigned*)smem;             // 3200 words (6400 u16 bins)
        unsigned* prc = pk + 3200;                  // 128 words (256 u16 rcnt)
        int* sxmin = (int*)(prc + 128);             // 4x256 int (17408 B total)
        int* sxmax = sxmin + NSEG;
        int* symin = sxmax + NSEG;
        int* symax = symin + NSEG;
        bool do_reg = (c == 0);
        for (int i = tid; i < 3200; i += 256) pk[i] = 0;
        if (do_reg) {
            if (tid < 128) prc[tid] = 0;
            sxmin[tid] = INT_MAX; sxmax[tid] = INT_MIN;
            symin[tid] = INT_MAX; symax[tid] = INT_MIN;
        }
        __syncthreads();
        const float4* ip = (const float4*)(img + ((size_t)b * 3 + c) * HW);
        const int4* lp = (const int4*)(lab + (size_t)bg * HW);
        for (int i = sp * 256 + tid; i < HW / 4; i += 256 * CHP) {
            float4 v4 = ip[i];
            int4 l4 = lp[i];
            int l0 = l4.x & 255, l1 = l4.y & 255, l2 = l4.z & 255, l3 = l4.w & 255;
            int b0 = (int)((float)l0 * 25.0f + v4.x * 24.0f);
            int b1 = (int)((float)l1 * 25.0f + v4.y * 24.0f);
            int b2 = (int)((float)l2 * 25.0f + v4.z * 24.0f);
            int b3 = (int)((float)l3 * 25.0f + v4.w * 24.0f);
            b0 = min(max(b0, 0), 6399); b1 = min(max(b1, 0), 6399);
            b2 = min(max(b2, 0), 6399); b3 = min(max(b3, 0), 6399);
            atomicAdd(&pk[b0 >> 1], 1u << ((b0 & 1) << 4));
            atomicAdd(&pk[b1 >> 1], 1u << ((b1 & 1) << 4));
            atomicAdd(&pk[b2 >> 1], 1u << ((b2 & 1) << 4));
            atomicAdd(&pk[b3 >> 1], 1u << ((b3 & 1) << 4));
            if (do_reg) {
                int p = i << 2;
                int y = p >> 9, x = p & 511;
                atomicAdd(&prc[l0 >> 1], 1u << ((l0 & 1) << 4));
                atomicAdd(&prc[l1 >> 1], 1u << ((l1 & 1) << 4));
                atomicAdd(&prc[l2 >> 1], 1u << ((l2 & 1) << 4));
                atomicAdd(&prc[l3 >> 1], 1u << ((l3 & 1) << 4));
                atomicMin(&sxmin[l0], x);     atomicMax(&sxmax[l0], x);
                atomicMin(&sxmin[l1], x + 1); atomicMax(&sxmax[l1], x + 1);
                atomicMin(&sxmin[l2], x + 2); atomicMax(&sxmax[l2], x + 2);
                atomicMin(&sxmin[l3], x + 3); atomicMax(&sxmax[l3], x + 3);
                atomicMin(&symin[l0], y); atomicMax(&symax[l0], y);
                atomicMin(&symin[l1], y); atomicMax(&symax[l1], y);
                atomicMin(&symin[l2], y); atomicMax(&symax[l2], y);
                atomicMin(&symin[l3], y); atomicMax(&symax[l3], y);
            }
        }
        __syncthreads();
        unsigned* dst = chp_w + ((size_t)gy * CHP + sp) * 3200;
        for (int i = tid; i < 3200; i += 256) dst[i] = pk[i];
        if (do_reg) {
            size_t pi = (size_t)(bg * CHP + sp) * NSEG + tid;
            rsp[pi] = (prc[tid >> 1] >> ((tid & 1) << 4)) & 0xFFFFu;
            bxmin[pi] = sxmin[tid]; bxmax[pi] = sxmax[tid];
            bymin[pi] = symin[tid]; bymax[pi] = symax[tid];
        }
    }
}

// ==== K2 (r22): thist (1728, r21 body) || ch-final+rs+xywh riders (768) ====
// ch-final depends only on K1 -> rides K2's scheduling bubbles instead of
// waiting for K2 to drain (it was the K3 half with no K2 dependency).
__global__ __launch_bounds__(256) void k_hist(
    const float* __restrict__ maps, const unsigned char* __restrict__ lab8,
    const float* __restrict__ pmin, const float* __restrict__ pmax,
    unsigned* __restrict__ thp_w, const unsigned* __restrict__ chp_w,
    const unsigned* __restrict__ rsp,
    const int* __restrict__ bxmin, const int* __restrict__ bxmax,
    const int* __restrict__ bymin, const int* __restrict__ bymax,
    float* __restrict__ out)
{
    __shared__ __align__(16) unsigned char smem[22528];
    int bx = blockIdx.x;
    int tid = threadIdx.x;
    if (bx < 1728) {
        // ---- thist role ----
        unsigned* cnt = (unsigned*)smem;            // 5120 u32
        float* slo = (float*)(smem + 20480);
        float* shi = slo + 256;
        int gy = bx / THP;
        int split = bx - gy * THP;
        int gi = gy % 3;
        int r = gy / 3;
        int base = r & 1;
        int bd = r >> 1;
        int d = bd & 1;
        int bc = bd >> 1;
        int b = bc / 3;
        int m = base * 12 + bc * 2 + d;
        float mn, mx;
        mm_of_map(pmin, pmax, m, slo, shi, mn, mx);
        for (int i = tid; i < 5120; i += 256) cnt[i] = 0;
        __syncthreads();
        float hminp = fmaxf(mn, 0.f), denp = fmaxf(mx, 0.f) - hminp;
        float hminn = fminf(mn, 0.f), denn = fminf(mx, 0.f) - hminn;
        const float4* src = (const float4*)(maps + (size_t)m * HW);
        const unsigned* lp = (const unsigned*)(lab8 + (size_t)(b * 3 + gi) * HW);
        for (int i = split * 256 + tid; i < HW / 4; i += 256 * THP) {
            float4 v4 = src[i];
            unsigned l4 = lp[i];
#define TH1(V, SH)                                                     \
            {                                                          \
                float v = (V);                                         \
                bool ge = (v >= 0.f);                                  \
                float hm = ge ? hminp : hminn;                         \
                float dn = ge ? denp : denn;                           \
                float t9 = ((v - hm) / dn) * 9.0f;                     \
                int bi = (int)((float)((l4 >> SH) & 255u) * 10.0f + t9); \
                bi = min(max(bi, 0), 2559);                            \
                atomicAdd(&cnt[(ge ? 0 : 2560) + bi], 1u);             \
            }
            TH1(v4.x, 0) TH1(v4.y, 8) TH1(v4.z, 16) TH1(v4.w, 24)
#undef TH1
        }
        __syncthreads();
        unsigned* dst = thp_w + ((size_t)(gy * THP + split)) * 2560;
        for (int i = tid; i < 2560; i += 256)
            dst[i] = cnt[2 * i] | (cnt[2 * i + 1] << 16);
    } else {
        // ---- ch-final rider: 2 segs per block, LDS-staged parallel reduce ----
        unsigned (*crs)[32] = (unsigned (*)[32])smem;       // [2][32]
        int (*sxm)[32] = (int (*)[32])(smem + 256);
        int (*sxM)[32] = (int (*)[32])(smem + 512);
        int (*sym)[32] = (int (*)[32])(smem + 768);
        int (*syM)[32] = (int (*)[32])(smem + 1024);
        int j = bx - 1728;                 // [0,768)
        int seg0 = j * 2;
        int bg = seg0 >> 8;
        int s0 = seg0 & 255, s1 = s0 + 1;
        int g = tid >> 5, w = tid & 31;
        size_t base0 = (size_t)(bg * CHP + w) * NSEG;
        if (g == 0)      crs[0][w] = rsp[base0 + s0];
        else if (g == 1) sxm[0][w] = bxmin[base0 + s0];
        else if (g == 2) sxM[0][w] = bxmax[base0 + s0];
        else if (g == 3) sym[0][w] = bymin[base0 + s0];
        else if (g == 4) syM[0][w] = bymax[base0 + s0];
        else if (g == 5) crs[1][w] = rsp[base0 + s1];
        else if (g == 6) sxm[1][w] = bxmin[base0 + s1];
        else if (g == 7) sxM[1][w] = bxmax[base0 + s1];
        if (g == 0)      sym[1][w] = bymin[base0 + s1];
        else if (g == 1) syM[1][w] = bymax[base0 + s1];
        __syncthreads();
        int half = tid >> 7, t2 = tid & 127;
        int s = half ? s1 : s0;
        int seg = seg0 + half;
        if (t2 < 75) {
            unsigned rs = 0;
            #pragma unroll 4
            for (int p = 0; p < CHP; ++p) rs += crs[half][p];
            float rsf = (float)rs;
            int c = t2 / 25, cb = t2 - c * 25;
            int bin = s * 25 + cb;
            unsigned sum = 0;
            #pragma unroll 4
            for (int p = 0; p < CHP; ++p) {
                unsigned v = chp_w[((size_t)((bg * 3 + c) * CHP + p)) * 3200 + (bin >> 1)];
                sum += (v >> ((bin & 1) << 4)) & 0xFFFFu;
            }
            out[CH_OFF + (size_t)seg * 75 + t2] = (float)sum / (3.0f * rsf);
        } else if (t2 == 75) {
            unsigned rs = 0;
            #pragma unroll 4
            for (int p = 0; p < CHP; ++p) rs += crs[half][p];
            float rsf = (float)rs;
            out[seg] = rsf;
            int xmn = INT_MAX, xmx = INT_MIN, ymn = INT_MAX, ymx = INT_MIN;
            #pragma unroll 4
            for (int p = 0; p < CHP; ++p) {
                xmn = min(xmn, sxm[half][p]); xmx = max(xmx, sxM[half][p]);
                ymn = min(ymn, sym[half][p]); ymx = max(ymx, syM[half][p]);
            }
            if (!(rsf > 0.f)) { xmn = IW; ymn = IW; xmx = 0; ymx = 0; }
            float* xy = out + XY_OFF + (size_t)seg * 4;
            xy[0] = (float)xmn; xy[1] = (float)ymn;
            xy[2] = (float)(xmx - xmn); xy[3] = (float)(ymx - ymn);
        }
    }
}

// ==== K3 (r22): pure th-reduce, 576 blocks (32-label chunks) ====
// Sign-completion bins are within the label's own 10-bin range (mn<0<mx for
// every Scharr map: tp0=0, tn0=9) -> chunk-local; guard keeps exactness.
__global__ __launch_bounds__(256) void k_final(
    const unsigned* __restrict__ thp_w, const unsigned* __restrict__ rsp,
    const float* __restrict__ pmin, const float* __restrict__ pmax,
    float* __restrict__ out)
{
    __shared__ unsigned hist[640];     // [0,320) pos bins, [320,640) neg, 32 labels
    __shared__ unsigned srs[32];
    __shared__ float slo[256], shi[256];
    int tid = threadIdx.x;
    int bx = blockIdx.x;
    int gy = bx >> 3;
    int ck = bx & 7;
    int l0 = ck << 5;                  // first label of chunk
    int gi = gy % 3; int r = gy / 3; int base = r & 1;
    int bd = r >> 1; int d = bd & 1; int bc = bd >> 1;
    int b = bc / 3, c = bc - b * 3;
    int m = base * 12 + bc * 2 + d;
    int bg = b * 3 + gi;
    float mn, mx;
    mm_of_map(pmin, pmax, m, slo, shi, mn, mx);
    // reduce packed partials: 160 words/side for this chunk
    for (int w = tid; w < 320; w += 256) {
        int gw = (w < 160) ? (l0 * 5 + w) : (1280 + l0 * 5 + (w - 160));
        unsigned s0 = 0, s1 = 0;
        #pragma unroll 4
        for (int p = 0; p < THP; ++p) {
            unsigned v = thp_w[((size_t)(gy * THP + p)) * 2560 + gw];
            s0 += v & 0xFFFFu; s1 += v >> 16;
        }
        int bi = (w < 160) ? (2 * w) : (320 + 2 * (w - 160));
        hist[bi] = s0; hist[bi + 1] = s1;
    }
    if (tid < 32) {
        unsigned s = 0;
        #pragma unroll 4
        for (int p = 0; p < CHP; ++p) s += rsp[((size_t)(bg * CHP + p)) * NSEG + l0 + tid];
        srs[tid] = s;
    }
    __syncthreads();
    if (tid < 32) {
        int l = l0 + tid;   // this chunk's labels: sign-completion
        unsigned nge = 0;
        for (int tb = 0; tb < 10; ++tb) nge += hist[tid * 10 + tb];  // v>=0 count
        unsigned rsu = srs[tid];
        unsigned nlt = (rsu >= nge) ? (rsu - nge) : 0u;              // v<0 count
        float hminp = fmaxf(mn, 0.f), denp = fmaxf(mx, 0.f) - hminp;
        float hminn = fminf(mn, 0.f), denn = fminf(mx, 0.f) - hminn;
        float la = (float)l;
        float tp0 = ((0.0f - hminp) / denp) * 9.0f;  // pos bin of clipped (v<0)
        float tn0 = ((0.0f - hminn) / denn) * 9.0f;  // neg bin of clipped (v>=0)
        int g0off = l0 * 10;
        int bp = (int)(la * 10.0f + tp0); bp = min(max(bp, 0), 2559);
        int bn = (int)(la * 10.0f + tn0); bn = min(max(bn, 0), 2559);
        if (nlt && bp >= g0off && bp < g0off + 320) atomicAdd(&hist[bp - g0off], nlt);
        if (nge && bn >= g0off && bn < g0off + 320) atomicAdd(&hist[320 + bn - g0off], nge);
    }
    __syncthreads();
    for (int i = tid; i < 640; i += 256) {
        int pos = (i < 320);
        int rr = pos ? i : i - 320;
        int lseg = rr / 10, tb = rr % 10;
        int seg = l0 + lseg;
        int tt = base * 4 + (pos ? 0 : 2) + d;
        float rsf = (float)srs[lseg];
        out[TH_OFF + ((size_t)(bg * NSEG + seg) * 3 + c) * 80 + tt * 10 + tb] =
            (float)hist[i] / (24.0f * rsf);
    }
}

extern "C" void kernel_launch(void* const* d_in, const int* in_sizes, int n_in,
                              void* d_out, int out_size, void* d_ws, size_t ws_size,
                              hipStream_t stream) {
    const float* img = (const float*)d_in[0];
    const int* lab = (const int*)d_in[1];
    float* out = (float*)d_out;

    float* gmaps = (float*)d_ws;                        // 24 maps * 262144 f32 (25.2 MB)
    float* pmin = gmaps + (size_t)24 * HW;              // 24*NBLK
    float* pmax = pmin + 24 * NBLK;
    unsigned* thp_w = (unsigned*)(pmax + 24 * NBLK);    // 72*THP*2560 u32 (~17.7 MB, u16-packed)
    unsigned* chp_w = thp_w + (size_t)72 * THP * 2560;  // 18*CHP*3200 u32 (~7.4 MB, u16-packed)
    unsigned char* lab8 = (unsigned char*)(chp_w + (size_t)18 * CHP * 3200);  // 6*HW u8
    unsigned* rsp = (unsigned*)(lab8 + (size_t)6 * HW); // 6*CHP*256 u32
    int* bxmin = (int*)(rsp + 6 * CHP * NSEG);
    int* bxmax = bxmin + 6 * CHP * NSEG;
    int* bymin = bxmax + 6 * CHP * NSEG;
    int* bymax = bymin + 6 * CHP * NSEG;

    hipLaunchKernelGGL(k_front, dim3(2112), dim3(256), 0, stream,
                       img, lab, gmaps, pmin, pmax, lab8, chp_w, rsp, bxmin, bxmax, bymin, bymax);
    hipLaunchKernelGGL(k_hist, dim3(1728 + 768), dim3(256), 0, stream,
                       gmaps, lab8, pmin, pmax, thp_w, chp_w, rsp, bxmin, bxmax, bymin, bymax, out);
    hipLaunchKernelGGL(k_final, dim3(576), dim3(256), 0, stream,
                       thp_w, rsp, pmin, pmax, out);
}